// Round 5
// baseline (545.747 us; speedup 1.0000x reference)
//
#include <hip/hip_runtime.h>
#include <cmath>

typedef __bf16 bf16;
typedef __bf16 bf16x8 __attribute__((ext_vector_type(8)));
typedef __bf16 bf16x4 __attribute__((ext_vector_type(4)));
typedef float f32x4 __attribute__((ext_vector_type(4)));
typedef int i32x4 __attribute__((ext_vector_type(4)));

#define S_LEN 2048
#define QK_LD 3072       // NHEADS * 192
// softmax scale (1/sqrt(128)) * log2(e), folded into q-projection epilogue
#define Q_PRESCALE 0.12751742566146944f

__device__ __forceinline__ void async_copy16(const bf16* g, bf16* l) {
    __builtin_amdgcn_global_load_lds(
        (const __attribute__((address_space(1))) void*)g,
        (__attribute__((address_space(3))) void*)l, 16, 0, 0);
}

// ---------------- cast x (fp32) -> bf16 ----------------
__global__ __launch_bounds__(256) void cast_f32_bf16(const float* __restrict__ in,
                                                     bf16* __restrict__ out) {
    size_t i = ((size_t)blockIdx.x * 256 + threadIdx.x) * 8;
    float4 a = *(const float4*)(in + i);
    float4 b = *(const float4*)(in + i + 4);
    bf16x8 v;
    v[0] = (bf16)a.x; v[1] = (bf16)a.y; v[2] = (bf16)a.z; v[3] = (bf16)a.w;
    v[4] = (bf16)b.x; v[5] = (bf16)b.y; v[6] = (bf16)b.z; v[7] = (bf16)b.w;
    *(bf16x8*)(out + i) = v;
}

// ---------------- fused transpose-cast of all 7 weights, one dispatch ----------------
struct TSeg { const float* src; bf16* dst; int K, N, blk0; };
struct TArgs { TSeg s[7]; };

__global__ __launch_bounds__(256) void transpose_all(TArgs a) {
    __shared__ float tile[64][68];
    int b = blockIdx.x, si = 0;
#pragma unroll
    for (int i = 1; i < 7; ++i) if (b >= a.s[i].blk0) si = i;
    TSeg sg = a.s[si];
    int local = b - sg.blk0;
    int kTiles = sg.K >> 6;
    int kt = local % kTiles, nt = local / kTiles;
    int k0 = kt * 64, n0 = nt * 64;
    int K = sg.K, N = sg.N;
    int t = threadIdx.x;
#pragma unroll
    for (int i = 0; i < 4; ++i) {
        int c = t + i * 256;
        int r = c >> 4, off = (c & 15) * 4;
        float4 v = *(const float4*)(sg.src + (size_t)(k0 + r) * N + n0 + off);
        tile[r][off] = v.x; tile[r][off + 1] = v.y;
        tile[r][off + 2] = v.z; tile[r][off + 3] = v.w;
    }
    __syncthreads();
#pragma unroll
    for (int i = 0; i < 2; ++i) {
        int c = t + i * 256;
        int nr = c >> 3, koff = (c & 7) * 8;
        bf16x8 v;
#pragma unroll
        for (int j = 0; j < 8; ++j) v[j] = (bf16)tile[koff + j][nr];
        *(bf16x8*)(sg.dst + (size_t)(n0 + nr) * K + k0 + koff) = v;
    }
}

// ---------------- bias concat + rope table, one dispatch ----------------
__global__ __launch_bounds__(256) void setup_small(const float* __restrict__ bd,
                                                   const float* __restrict__ bqd,
                                                   const float* __restrict__ bkr,
                                                   const float* __restrict__ bqu,
                                                   const float* __restrict__ bqr,
                                                   float* __restrict__ bcat,
                                                   float2* __restrict__ tab) {
    if (blockIdx.x < 21) {
        int i = blockIdx.x * 256 + threadIdx.x;
        if (i < 512) bcat[i] = bd[i];
        else if (i < 1280) bcat[i] = bqd[i - 512];
        else if (i < 2304) bcat[i] = bkr[i - 1280];
        else if (i < 4352) bcat[i] = bqu[i - 2304];
        else if (i < 5376) bcat[i] = bqr[i - 4352];
    } else {
        int id = (blockIdx.x - 21) * 256 + threadIdx.x;   // 65536
        int s = id >> 5, i = id & 31;
        float f = expf(-0.2878231366242557f * (float)i);  // ln(10000)/32
        float ang = (float)s * f;
        tab[id] = make_float2(cosf(ang), sinf(ang));
    }
}

// ---------------- m97-style bf16 GEMM core with fused epilogues ----------------
// mode 1: fp32 out0, stride Ndim
// mode 4: col<1280 -> bf16 out0 (xproj, stride 2304); col>=1280 -> rope -> out1 (kbuf)
// mode 5: col<2048 -> head-scatter out0 (qbuf); col>=2048 -> rope -> out0 (qbuf)
//         (both scaled by Q_PRESCALE)
// mode 6: head-scatter out0 (kbuf) + transposed pack out1 (vt[bh][d][s])
__device__ __forceinline__ void gemm_core(const bf16* __restrict__ A, int lda,
                                          const bf16* __restrict__ Bt,
                                          const float* __restrict__ bias,
                                          void* __restrict__ out0,
                                          void* __restrict__ out1,
                                          int Ndim, int Kdim, int mode,
                                          const float2* __restrict__ tab,
                                          int bn, int bm, bf16* As, bf16* Bs) {
    int t = threadIdx.x;
    int w = t >> 6, lane = t & 63;
    int wm = (w >> 1) * 64, wn = (w & 1) * 64;
    int l15 = lane & 15, q4 = lane >> 4;
    f32x4 acc[4][4] = {};

    int lrow = lane >> 2;
    int lcol = (lane & 3) * 8;
    int c0 = w * 2, c1 = w * 2 + 1;
    const bf16* aS0 = A  + (size_t)(bm * 128 + c0 * 16 + lrow) * lda + lcol;
    const bf16* aS1 = A  + (size_t)(bm * 128 + c1 * 16 + lrow) * lda + lcol;
    const bf16* bS0 = Bt + (size_t)(bn * 128 + c0 * 16 + lrow) * Kdim + lcol;
    const bf16* bS1 = Bt + (size_t)(bn * 128 + c1 * 16 + lrow) * Kdim + lcol;
    bf16* aD0 = &As[c0 * 512]; bf16* aD1 = &As[c1 * 512];
    bf16* bD0 = &Bs[c0 * 512]; bf16* bD1 = &Bs[c1 * 512];

    for (int kt = 0; kt < Kdim; kt += 32) {
        async_copy16(aS0 + kt, aD0);
        async_copy16(aS1 + kt, aD1);
        async_copy16(bS0 + kt, bD0);
        async_copy16(bS1 + kt, bD1);
        __syncthreads();
        bf16x8 af[4], bfr[4];
#pragma unroll
        for (int mb = 0; mb < 4; ++mb)
            af[mb] = *(const bf16x8*)&As[(wm + mb * 16 + l15) * 32 + q4 * 8];
#pragma unroll
        for (int nb = 0; nb < 4; ++nb)
            bfr[nb] = *(const bf16x8*)&Bs[(wn + nb * 16 + l15) * 32 + q4 * 8];
#pragma unroll
        for (int mb = 0; mb < 4; ++mb)
#pragma unroll
            for (int nb = 0; nb < 4; ++nb)
                acc[mb][nb] = __builtin_amdgcn_mfma_f32_16x16x32_bf16(
                    af[mb], bfr[nb], acc[mb][nb], 0, 0, 0);
        __syncthreads();
    }

#pragma unroll
    for (int mb = 0; mb < 4; ++mb) {
        int row = bm * 128 + wm + mb * 16 + q4 * 4;
#pragma unroll
        for (int nb = 0; nb < 4; ++nb) {
            int col = bn * 128 + wn + nb * 16 + l15;
            float bv = bias[col];
            if (mode == 1) {
#pragma unroll
                for (int r = 0; r < 4; ++r)
                    ((float*)out0)[(size_t)(row + r) * Ndim + col] = acc[mb][nb][r] + bv;
            } else if (mode == 4) {
                if (col < 1280) {
#pragma unroll
                    for (int r = 0; r < 4; ++r)
                        ((bf16*)out0)[(size_t)(row + r) * 2304 + col] =
                            (bf16)(acc[mb][nb][r] + bv);
                } else {
                    int rel = col - 1280;
                    int hh = rel >> 6, idx = rel & 63, ii = idx >> 1, odd = idx & 1;
#pragma unroll
                    for (int r = 0; r < 4; ++r) {
                        float vv = acc[mb][nb][r] + bv;
                        float pp = __shfl_xor(vv, 1, 64);
                        float2 cs = tab[((row + r) & 2047) * 32 + ii];
                        float o = vv * cs.x + (odd ? pp * cs.y : -pp * cs.y);
                        ((bf16*)out1)[(size_t)(row + r) * QK_LD + hh * 192 + 128 + idx] =
                            (bf16)o;
                    }
                }
            } else if (mode == 5) {
                if (col < 2048) {
                    int hh = col >> 7, dd = col & 127;
#pragma unroll
                    for (int r = 0; r < 4; ++r)
                        ((bf16*)out0)[(size_t)(row + r) * QK_LD + hh * 192 + dd] =
                            (bf16)((acc[mb][nb][r] + bv) * Q_PRESCALE);
                } else {
                    int rel = col - 2048;
                    int hh = rel >> 6, idx = rel & 63, ii = idx >> 1, odd = idx & 1;
#pragma unroll
                    for (int r = 0; r < 4; ++r) {
                        float vv = acc[mb][nb][r] + bv;
                        float pp = __shfl_xor(vv, 1, 64);
                        float2 cs = tab[((row + r) & 2047) * 32 + ii];
                        float o = vv * cs.x + (odd ? pp * cs.y : -pp * cs.y);
                        ((bf16*)out0)[(size_t)(row + r) * QK_LD + hh * 192 + 128 + idx] =
                            (bf16)(o * Q_PRESCALE);
                    }
                }
            } else {   // mode 6: kv_up -> kbuf scatter + vt transpose-pack
                int hh = col >> 7, dd = col & 127;
                bf16x4 pack;
#pragma unroll
                for (int r = 0; r < 4; ++r) {
                    float vv = acc[mb][nb][r] + bv;
                    ((bf16*)out0)[(size_t)(row + r) * QK_LD + hh * 192 + dd] = (bf16)vv;
                    pack[r] = (bf16)vv;
                }
                int bidx = row >> 11, srow = row & 2047;
                *(bf16x4*)((bf16*)out1 +
                           ((size_t)(bidx * 16 + hh) * 128 + dd) * S_LEN + srow) = pack;
            }
        }
    }
}

__global__ __launch_bounds__(256) void gemm_bt(const bf16* __restrict__ A, int lda,
                                               const bf16* __restrict__ Bt,
                                               const float* __restrict__ bias,
                                               void* __restrict__ out0,
                                               void* __restrict__ out1,
                                               int Ndim, int Kdim, int mode,
                                               const float2* __restrict__ tab) {
    __shared__ bf16 As[128 * 32];
    __shared__ bf16 Bs[128 * 32];
    gemm_core(A, lda, Bt, bias, out0, out1, Ndim, Kdim, mode, tab,
              blockIdx.x, blockIdx.y, As, Bs);
}

// fused up-projection GEMMs: bn<16 -> kv_up (mode 6, K=512); bn>=16 -> q_up (mode 5, K=768)
__global__ __launch_bounds__(256) void gemm_up(const bf16* __restrict__ xproj,
                                               const bf16* __restrict__ WuT,
                                               const float* __restrict__ bu,
                                               void* __restrict__ kbuf,
                                               void* __restrict__ vt,
                                               const bf16* __restrict__ W2T,
                                               const float* __restrict__ bq,
                                               void* __restrict__ qbuf,
                                               const float2* __restrict__ tab) {
    __shared__ bf16 As[128 * 32];
    __shared__ bf16 Bs[128 * 32];
    int bn = blockIdx.x;
    if (bn < 16)
        gemm_core(xproj, 2304, WuT, bu, kbuf, vt, 2048, 512, 6, tab,
                  bn, blockIdx.y, As, Bs);
    else
        gemm_core(xproj + 512, 2304, W2T, bq, qbuf, nullptr, 3072, 768, 5, tab,
                  bn - 16, blockIdx.y, As, Bs);
}

// ---------------- attention v5: 2x2 quadrant partition, halved LDS read traffic ----
// wave (wq, wk): QK^T quadrant [k: wk*32..+32] x [q: wq*64..+64];
//                PV quadrant   [q: wq*64..+64] x [d: wk*64..+64].
// Q pre-scaled by (1/sqrt(128))*log2(e) in gemm epilogue -> softmax uses exp2.
__global__ __launch_bounds__(256, 2) void attn(const bf16* __restrict__ qbuf,
                                               const bf16* __restrict__ kbuf,
                                               const bf16* __restrict__ vt,
                                               bf16* __restrict__ attnout) {
    __shared__ bf16 Ks[64 * 200];       // 64 keys x 192 (pad 200)
    __shared__ bf16 Vs[128 * 72];       // 128 d x 64 keys (pad 72)
    __shared__ bf16 Ps[128 * 72];       // 128 q x 64 keys (pad 72)
    __shared__ float denomLds[2][128];
    int bh = blockIdx.x;                // fastest -> id%8 = bh%8 -> XCD affinity for K/V
    int qt = blockIdx.y;
    int b = bh >> 4, h = bh & 15;
    int t = threadIdx.x, w = t >> 6, lane = t & 63;
    int wq = w >> 1, wk = w & 1;
    int l15 = lane & 15, q4 = lane >> 4;

    // Q: 64 rows x 192 per wave, register-resident (B-operand frags)
    bf16x8 qf[4][6];
    {
        size_t base = (size_t)(b * S_LEN + qt * 128 + wq * 64) * QK_LD + h * 192;
#pragma unroll
        for (int mb = 0; mb < 4; ++mb)
#pragma unroll
            for (int c = 0; c < 6; ++c)
                qf[mb][c] = *(const bf16x8*)(qbuf + base +
                            (size_t)(mb * 16 + l15) * QK_LD + c * 32 + q4 * 8);
    }

    f32x4 oacc[4][4] = {};
    float denom[4] = {};
    const bf16* kb_base = kbuf + (size_t)b * S_LEN * QK_LD + h * 192;
    const bf16* vt_base = vt + (size_t)bh * 128 * S_LEN;

    int kr_[6], ko_[6], vd_[4], vo_[4];
#pragma unroll
    for (int i = 0; i < 6; ++i) { int c = t + (i << 8); kr_[i] = c / 24; ko_[i] = (c % 24) * 8; }
#pragma unroll
    for (int i = 0; i < 4; ++i) { int c = t + (i << 8); vd_[i] = c >> 3; vo_[i] = (c & 7) * 8; }

    i32x4 kreg[6], vreg[4];
#pragma unroll
    for (int i = 0; i < 6; ++i)
        kreg[i] = *(const i32x4*)(kb_base + (size_t)kr_[i] * QK_LD + ko_[i]);
#pragma unroll
    for (int i = 0; i < 4; ++i)
        vreg[i] = *(const i32x4*)(vt_base + (size_t)vd_[i] * S_LEN + vo_[i]);

    for (int kt = 0; kt < 32; ++kt) {
        __syncthreads();                 // prior iter's Ks/Vs readers done
#pragma unroll
        for (int i = 0; i < 6; ++i) *(i32x4*)&Ks[kr_[i] * 200 + ko_[i]] = kreg[i];
#pragma unroll
        for (int i = 0; i < 4; ++i) *(i32x4*)&Vs[vd_[i] * 72 + vo_[i]] = vreg[i];
        __syncthreads();
        if (kt < 31) {                   // register prefetch of next tile
#pragma unroll
            for (int i = 0; i < 6; ++i)
                kreg[i] = *(const i32x4*)(kb_base +
                          (size_t)((kt + 1) * 64 + kr_[i]) * QK_LD + ko_[i]);
#pragma unroll
            for (int i = 0; i < 4; ++i)
                vreg[i] = *(const i32x4*)(vt_base +
                          (size_t)vd_[i] * S_LEN + (kt + 1) * 64 + vo_[i]);
        }

        // QK^T quadrant: S^T [32k x 64q]; nk-split to shorten sacc live range
#pragma unroll
        for (int nk = 0; nk < 2; ++nk) {
            f32x4 sacc[4] = {};
#pragma unroll
            for (int c = 0; c < 6; ++c) {
                bf16x8 kb = *(const bf16x8*)&Ks[(wk * 32 + nk * 16 + l15) * 200 +
                                                c * 32 + q4 * 8];
#pragma unroll
                for (int mb = 0; mb < 4; ++mb)
                    sacc[mb] = __builtin_amdgcn_mfma_f32_16x16x32_bf16(
                        kb, qf[mb][c], sacc[mb], 0, 0, 0);
            }
            // lane holds S^T[k = wk*32+nk*16+q4*4+r][q = wq*64+mb*16+l15]
#pragma unroll
            for (int mb = 0; mb < 4; ++mb) {
                bf16x4 pk;
#pragma unroll
                for (int r = 0; r < 4; ++r) {
                    float p = exp2f(fminf(sacc[mb][r], 80.0f));
                    denom[mb] += p;
                    pk[r] = (bf16)p;
                }
                *(bf16x4*)&Ps[(wq * 64 + mb * 16 + l15) * 72 +
                              wk * 32 + nk * 16 + q4 * 4] = pk;
            }
        }
        __syncthreads();                 // sibling wave's P half visible

        // PV quadrant: O[64q x 64d] over 64 keys
#pragma unroll
        for (int kc = 0; kc < 2; ++kc) {
            bf16x8 pa[4];
#pragma unroll
            for (int mb = 0; mb < 4; ++mb)
                pa[mb] = *(const bf16x8*)&Ps[(wq * 64 + mb * 16 + l15) * 72 +
                                             kc * 32 + q4 * 8];
#pragma unroll
            for (int nd = 0; nd < 4; ++nd) {
                bf16x8 vb = *(const bf16x8*)&Vs[(wk * 64 + nd * 16 + l15) * 72 +
                                                kc * 32 + q4 * 8];
#pragma unroll
                for (int mb = 0; mb < 4; ++mb)
                    oacc[mb][nd] = __builtin_amdgcn_mfma_f32_16x16x32_bf16(
                        pa[mb], vb, oacc[mb][nd], 0, 0, 0);
            }
        }
    }

    // denom: lane has partial for q = wq*64+mb*16+l15 over its (wk,q4) keys.
    // Sum over q4 groups, then combine wk halves via LDS.
#pragma unroll
    for (int mb = 0; mb < 4; ++mb) {
        denom[mb] += __shfl_xor(denom[mb], 16, 64);
        denom[mb] += __shfl_xor(denom[mb], 32, 64);
    }
    if (q4 == 0) {
#pragma unroll
        for (int mb = 0; mb < 4; ++mb)
            denomLds[wk][wq * 64 + mb * 16 + l15] = denom[mb];
    }
    __syncthreads();

#pragma unroll
    for (int mb = 0; mb < 4; ++mb)
#pragma unroll
        for (int r = 0; r < 4; ++r) {
            int rl = wq * 64 + mb * 16 + q4 * 4 + r;
            float inv = 1.0f / (denomLds[0][rl] + denomLds[1][rl]);
            int row = qt * 128 + rl;
#pragma unroll
            for (int nd = 0; nd < 4; ++nd) {
                int col = h * 128 + wk * 64 + nd * 16 + l15;
                attnout[(size_t)(b * S_LEN + row) * 2048 + col] =
                    (bf16)(oacc[mb][nd][r] * inv);
            }
        }
}

extern "C" void kernel_launch(void* const* d_in, const int* in_sizes, int n_in,
                              void* d_out, int out_size, void* d_ws, size_t ws_size,
                              hipStream_t stream) {
    const float* x   = (const float*)d_in[0];
    const float* Wd  = (const float*)d_in[1];
    const float* bd  = (const float*)d_in[2];
    const float* Wu  = (const float*)d_in[3];
    const float* bu  = (const float*)d_in[4];
    const float* Wqd = (const float*)d_in[5];
    const float* bqd = (const float*)d_in[6];
    const float* Wqu = (const float*)d_in[7];
    const float* bqu = (const float*)d_in[8];
    const float* Wqr = (const float*)d_in[9];
    const float* bqr = (const float*)d_in[10];
    const float* Wkr = (const float*)d_in[11];
    const float* bkr = (const float*)d_in[12];
    const float* Wo  = (const float*)d_in[13];
    const float* bo  = (const float*)d_in[14];
    float* out = (float*)d_out;

    char* p = (char*)d_ws;
    auto alloc = [&](size_t n) { char* r = p; p += (n + 255) & ~(size_t)255; return r; };
    bf16* xb    = (bf16*)alloc((size_t)4096 * 2048 * 2);
    bf16* W1T   = (bf16*)alloc((size_t)2304 * 2048 * 2);   // [Wd|Wqd|Wkr]^T
    bf16* W2T   = (bf16*)alloc((size_t)3072 * 768 * 2);    // [Wqu|Wqr]^T
    bf16* WuT   = (bf16*)alloc((size_t)2048 * 512 * 2);
    bf16* WoT   = (bf16*)alloc((size_t)2048 * 2048 * 2);
    bf16* xproj = (bf16*)alloc((size_t)4096 * 2304 * 2);   // [kvc|qcmp]
    bf16* qbuf  = (bf16*)alloc((size_t)4096 * 3072 * 2);
    bf16* kbuf  = (bf16*)alloc((size_t)4096 * 3072 * 2);
    bf16* vt    = (bf16*)alloc((size_t)32 * 128 * 2048 * 2);
    bf16* aout  = (bf16*)alloc((size_t)4096 * 2048 * 2);
    float* bcat = (float*)alloc((size_t)5376 * 4);
    float2* tab = (float2*)alloc((size_t)65536 * 8);

    cast_f32_bf16<<<dim3(4096), dim3(256), 0, stream>>>(x, xb);

    TArgs ta;
    ta.s[0] = {Wd,  W1T,                       2048, 512,  0};
    ta.s[1] = {Wqd, W1T + (size_t)512 * 2048,  2048, 768,  256};
    ta.s[2] = {Wkr, W1T + (size_t)1280 * 2048, 2048, 1024, 640};
    ta.s[3] = {Wqu, W2T,                       768,  2048, 1152};
    ta.s[4] = {Wqr, W2T + (size_t)2048 * 768,  768,  1024, 1536};
    ta.s[5] = {Wu,  WuT,                       512,  2048, 1728};
    ta.s[6] = {Wo,  WoT,                       2048, 2048, 1984};
    transpose_all<<<dim3(3008), dim3(256), 0, stream>>>(ta);
    setup_small<<<dim3(277), dim3(256), 0, stream>>>(bd, bqd, bkr, bqu, bqr, bcat, tab);

    // GEMM1: x @ [Wd|Wqd|Wkr] -> xproj cols 0..1279, rope(k_r) -> kbuf
    gemm_bt<<<dim3(18, 32), dim3(256), 0, stream>>>(xb, 2048, W1T, bcat,
                                                    xproj, kbuf, 2304, 2048, 4, tab);
    // fused: kvc @ Wu -> kbuf + vt; qcmp @ [Wqu|Wqr] -> qbuf (+rope, pre-scaled)
    gemm_up<<<dim3(40, 32), dim3(256), 0, stream>>>(xproj, WuT, bu, kbuf, vt,
                                                    W2T, bcat + 2304, qbuf, tab);

    attn<<<dim3(32, 16), dim3(256), 0, stream>>>(qbuf, kbuf, vt, aout);

    gemm_bt<<<dim3(16, 32), dim3(256), 0, stream>>>(aout, 2048, WoT, bo,
                                                    out, nullptr, 2048, 2048, 1, tab);
}